// Round 9
// baseline (54.861 us; speedup 1.0000x reference)
//
#include <hip/hip_runtime.h>
#include <hip/hip_cooperative_groups.h>
#include <math.h>

namespace cg = cooperative_groups;

#define NYX 192
#define NNODE 193
#define L_NODES (NNODE*NNODE)     /* 37249 */
#define NPAIR 11
#define NB 2
#define NCH 12
#define NZ 3                      /* channel-groups: z=0 pairs 0-3, z=1 pairs 4-7, z=2 pairs 8-10 */
#define NGRP (NZ*NB)              /* 6 partial groups */
#define RPB 6                     /* node rows per block = waves per block */
#define NBLKX 33                  /* ceil(193/6) */
#define RECF 12                   /* floats per record (48B, float4-aligned) */
#define LN2f 0.69314718055994530942f

/* ws: float rec[NGRP][NBLKX][RECF]  (6*33*12*4 = 9504 B); records fully
   rewritten via atomicExch every call -> no zero-init needed, replay-safe. */

__device__ __forceinline__ void sdice_compute(const float* __restrict__ pred,
                                              const float* __restrict__ labels,
                                              float* __restrict__ rec,
                                              const float areas[256],
                                              float sred[RPB][10])
{
    const int z    = blockIdx.z;
    const int b    = blockIdx.y;
    const int lane = threadIdx.x & 63;
    const int wrow = threadIdx.x >> 6;        /* 0..5: one wave == one node row */
    const int j    = blockIdx.x * RPB + wrow; /* node row (guard j<193) */
    const int t    = lane;                    /* x-group: nodes 4t..4t+3 */
    const int np   = (z == 2) ? 3 : 4;
    const int nch  = np + 1;
    const int c0   = z * 4;

    float numA = 0.f, denA = 0.f;
    float bceA[4] = {0.f, 0.f, 0.f, 0.f};
    float cntA[4] = {0.f, 0.f, 0.f, 0.f};

    const bool act = (j < NNODE) && (t < 48);

    if (act) {
        const int y0 = (j >= 1) ? (j - 1) : 0;        /* clamped rows -> loads always valid */
        const int y1 = (j <= NYX - 1) ? j : (NYX - 1);
        const int xo = t * 4;

        float    sigP[2][6], bcvP[2][6], sigC[2][6], bcvC[2][6];
        unsigned w5P[2], w5C[2];

        for (int cc = 0; cc < nch; ++cc) {            /* wave-uniform runtime loop */
            const int ch = c0 + cc;
            const size_t base = (size_t)(b * NCH + ch) * (NYX * NYX);

            #pragma unroll
            for (int r = 0; r < 2; ++r) {
                const int  yy = r ? y1 : y0;
                const bool mm = r ? (j <= NYX - 1) : (j >= 1);
                const float4 p4 = *reinterpret_cast<const float4*>(pred   + base + (size_t)yy * NYX + xo);
                const float4 l4 = *reinterpret_cast<const float4*>(labels + base + (size_t)yy * NYX + xo);
                const float pe[4] = {p4.x, p4.y, p4.z, p4.w};
                const float le[4] = {l4.x, l4.y, l4.z, l4.w};
                unsigned bits = 0;
                #pragma unroll
                for (int e = 0; e < 4; ++e) {
                    const float pv = mm ? pe[e] : 0.f;     /* row-OOB -> padded zeros */
                    const float lv = mm ? le[e] : 0.f;
                    bits |= ((unsigned)lv) << e;
                    const float s = __builtin_amdgcn_rcpf(1.f + __expf(-pv));
                    sigC[r][e + 1] = mm ? s : 0.f;         /* pad AFTER sigmoid -> 0 */
                    bcvC[r][e + 1] = fmaxf(pv, 0.f) - pv * lv + __logf(1.f + __expf(-fabsf(pv)));
                }
                w5C[r] = bits << 1;
                sigC[r][5] = 0.f;       /* x = 4t+4 slot, used only by node 192 (x OOB) */
                bcvC[r][5] = LN2f;

                /* x = 4t-1 halo from lane-1 (lane 0 is the real x=0 border) */
                const float    sw = __shfl_up(sigC[r][4], 1);
                const float    bw = __shfl_up(bcvC[r][4], 1);
                const unsigned ww = (unsigned)__shfl_up((int)w5C[r], 1);
                sigC[r][0] = (t == 0) ? 0.f  : sw;
                bcvC[r][0] = (t == 0) ? LN2f : bw;
                w5C[r]    |= (t == 0) ? 0u   : ((ww >> 4) & 1u);
            }

            if (cc > 0) {
                const int pp = cc - 1;
                float pnum = 0.f, pden = 0.f, pbce = 0.f, pcnt = 0.f;
                #pragma unroll
                for (int i = 0; i < 5; ++i) {
                    if (i < 4 || t == 47) {               /* node ix=192 only on lane 47 */
                        const unsigned b0 = (w5P[0] >> i) & 1u, b1 = (w5P[0] >> (i + 1)) & 1u;
                        const unsigned b2 = (w5P[1] >> i) & 1u, b3 = (w5P[1] >> (i + 1)) & 1u;
                        const unsigned b4 = (w5C[0] >> i) & 1u, b5 = (w5C[0] >> (i + 1)) & 1u;
                        const unsigned b6 = (w5C[1] >> i) & 1u, b7 = (w5C[1] >> (i + 1)) & 1u;
                        const unsigned byte = b0 | (b1 << 1) | (b2 << 2) | (b3 << 3)
                                            | (b4 << 4) | (b5 << 5) | (b6 << 6) | (b7 << 7);
                        const float e0 = sigP[0][i]     - (float)b0;
                        const float e1 = sigP[0][i + 1] - (float)b1;
                        const float e2 = sigP[1][i]     - (float)b2;
                        const float e3 = sigP[1][i + 1] - (float)b3;
                        const float e4 = sigC[0][i]     - (float)b4;
                        const float e5 = sigC[0][i + 1] - (float)b5;
                        const float e6 = sigC[1][i]     - (float)b6;
                        const float e7 = sigC[1][i + 1] - (float)b7;
                        const float d2 = ((e0*e0 + e1*e1) + (e2*e2 + e3*e3))
                                       + ((e4*e4 + e5*e5) + (e6*e6 + e7*e7));
                        const float w  = 1.f - sqrtf(d2) * (1.f / 16.f);
                        const float la = areas[byte];
                        pnum += w * la;
                        pden += la;
                        const bool msk = (byte == 0u) || (byte == 255u);
                        if (msk) {
                            pcnt += 1.f;
                            pbce += ((bcvP[0][i] + bcvP[0][i+1]) + (bcvP[1][i] + bcvP[1][i+1]))
                                  + ((bcvC[0][i] + bcvC[0][i+1]) + (bcvC[1][i] + bcvC[1][i+1]));
                        }
                    }
                }
                numA += pnum; denA += pden;
                bceA[pp] += pbce; cntA[pp] += pcnt;
            }

            #pragma unroll
            for (int r = 0; r < 2; ++r) {
                w5P[r] = w5C[r];
                #pragma unroll
                for (int q = 0; q < 6; ++q) { sigP[r][q] = sigC[r][q]; bcvP[r][q] = bcvC[r][q]; }
            }
        }
    }

    float v[10] = {numA, denA, bceA[0], bceA[1], bceA[2], bceA[3], cntA[0], cntA[1], cntA[2], cntA[3]};
    #pragma unroll
    for (int off = 32; off > 0; off >>= 1) {
        #pragma unroll
        for (int q = 0; q < 10; ++q) v[q] += __shfl_down(v[q], off);
    }
    if (lane == 0) {
        #pragma unroll
        for (int q = 0; q < 10; ++q) sred[wrow][q] = v[q];
    }
    __syncthreads();
    if (threadIdx.x == 0) {
        float s[10];
        #pragma unroll
        for (int q = 0; q < 10; ++q)
            s[q] = ((sred[0][q] + sred[1][q]) + (sred[2][q] + sred[3][q])) + (sred[4][q] + sred[5][q]);
        /* coherence-point writes into this block's own record: no init, no contention */
        float* rp = rec + (size_t)((z * NB + b) * NBLKX + blockIdx.x) * RECF;
        #pragma unroll
        for (int q = 0; q < 10; ++q) atomicExch(rp + q, s[q]);
        asm volatile("s_waitcnt vmcnt(0)" ::: "memory");  /* exchanges done before barrier arrive */
    }
}

__device__ __forceinline__ void sdice_finish(const float* __restrict__ rec,
                                             const float* __restrict__ area,
                                             float* __restrict__ out,
                                             float gsb[NGRP][10])
{
    const int wrow = threadIdx.x >> 6;   /* 6 waves <-> 6 groups */
    const int lane = threadIdx.x & 63;

    float v[10];
    #pragma unroll
    for (int q = 0; q < 10; ++q) v[q] = 0.f;
    if (lane < NBLKX) {
        const float4* r4 = reinterpret_cast<const float4*>(rec + (size_t)(wrow * NBLKX + lane) * RECF);
        const float4 a = r4[0], bb = r4[1], c = r4[2];
        v[0]=a.x; v[1]=a.y; v[2]=a.z; v[3]=a.w;
        v[4]=bb.x; v[5]=bb.y; v[6]=bb.z; v[7]=bb.w;
        v[8]=c.x; v[9]=c.y;
    }
    #pragma unroll
    for (int off = 32; off > 0; off >>= 1) {
        #pragma unroll
        for (int q = 0; q < 10; ++q) v[q] += __shfl_down(v[q], off);
    }
    if (lane == 0) {
        #pragma unroll
        for (int q = 0; q < 10; ++q) gsb[wrow][q] = v[q];
    }
    __syncthreads();
    if (threadIdx.x == 0) {
        const float a1 = area[1];   /* pred_byte == 1 everywhere (strict '>' in fori_loop) */
        float dice_sum = 0.f, vol_sum = 0.f;
        for (int bb = 0; bb < NB; ++bb) {
            float numb = 0.f, denb = 0.f, volb = 0.f;
            for (int zz = 0; zz < NZ; ++zz) {
                const int g2 = zz * NB + bb;
                const int npz = (zz == 2) ? 3 : 4;
                numb += 2.0f * gsb[g2][0];
                denb += gsb[g2][1];
                for (int pp = 0; pp < npz; ++pp)
                    volb += gsb[g2][2 + pp] / (8.0f * gsb[g2][6 + pp]);
            }
            denb += (float)NPAIR * (float)L_NODES * a1;
            dice_sum += 1.0f - (numb + 0.001f) / (denb + 0.001f);
            vol_sum  += volb;
        }
        out[0] = dice_sum / (float)NB + vol_sum / (float)NB;
    }
}

__global__ __launch_bounds__(384) void sdice_coop(const float* __restrict__ pred,
                                                  const float* __restrict__ labels,
                                                  const float* __restrict__ area,
                                                  float* __restrict__ rec,
                                                  float* __restrict__ out)
{
    __shared__ float areas[256];
    __shared__ float sred[RPB][10];
    __shared__ float gsb[NGRP][10];
    if (threadIdx.x < 256) areas[threadIdx.x] = area[threadIdx.x];
    __syncthreads();

    sdice_compute(pred, labels, rec, areas, sred);

    cg::this_grid().sync();   /* runtime-managed barrier state: no init, replay-safe */

    if (blockIdx.x == 0 && blockIdx.y == 0 && blockIdx.z == 0)
        sdice_finish(rec, area, out, gsb);
}

/* ---- fallback: proven two-kernel path (used only if coop launch fails) ---- */

__global__ __launch_bounds__(384) void sdice_node_fb(const float* __restrict__ pred,
                                                     const float* __restrict__ labels,
                                                     const float* __restrict__ area,
                                                     float* __restrict__ rec)
{
    __shared__ float areas[256];
    __shared__ float sred[RPB][10];
    if (threadIdx.x < 256) areas[threadIdx.x] = area[threadIdx.x];
    __syncthreads();
    sdice_compute(pred, labels, rec, areas, sred);
}

__global__ __launch_bounds__(384) void sdice_final_fb(const float* __restrict__ rec,
                                                      const float* __restrict__ area,
                                                      float* __restrict__ out)
{
    __shared__ float gsb[NGRP][10];
    sdice_finish(rec, area, out, gsb);
}

extern "C" void kernel_launch(void* const* d_in, const int* in_sizes, int n_in,
                              void* d_out, int out_size, void* d_ws, size_t ws_size,
                              hipStream_t stream) {
    const float* pred   = (const float*)d_in[0];
    const float* labels = (const float*)d_in[1];
    const float* area   = (const float*)d_in[2];
    float* out = (float*)d_out;
    float* rec = (float*)d_ws;

    dim3 grid(NBLKX, NB, NZ), blk(384, 1, 1);
    void* args[5] = {(void*)&pred, (void*)&labels, (void*)&area, (void*)&rec, (void*)&out};
    const hipError_t e = hipLaunchCooperativeKernel((void*)sdice_coop, grid, blk,
                                                    args, 0u, stream);
    if (e != hipSuccess) {   /* deterministic per-deployment: falls back every call */
        sdice_node_fb<<<grid, blk, 0, stream>>>(pred, labels, area, rec);
        sdice_final_fb<<<1, blk, 0, stream>>>(rec, area, out);
    }
}

// Round 10
// 19.465 us; speedup vs baseline: 2.8184x; 2.8184x over previous
//
#include <hip/hip_runtime.h>
#include <math.h>

#define NYX 192
#define NNODE 193
#define L_NODES (NNODE*NNODE)     /* 37249 */
#define NPAIR 11
#define NB 2
#define NCH 12
#define NZ 3                      /* channel-groups: z=0 pairs 0-3, z=1 pairs 4-7, z=2 pairs 8-10 */
#define NGRP (NZ*NB)              /* 6 partial groups */
#define NBLK 49                   /* row-blocks: ceil(193/4) */
#define RECF 12                   /* floats per partial record: num,den,bce[4],cnt[4],pad2 */
#define LN2f 0.69314718055994530942f

/* ws: float partials[NGRP*NBLK*RECF]  (6*49*12*4 = 14112 B); fully rewritten
   each call (non-atomic stores) -> no zero-init, replay-deterministic. */

__global__ __launch_bounds__(256) void sdice_node(const float* __restrict__ pred,
                                                  const float* __restrict__ labels,
                                                  const float* __restrict__ area,
                                                  float* __restrict__ partials)
{
    const int z    = blockIdx.z;             /* channel group */
    const int b    = blockIdx.y;
    const int lane = threadIdx.x & 63;       /* one wave == one node row; lanes 0..47 active */
    const int wrow = threadIdx.x >> 6;
    const int j    = blockIdx.x * 4 + wrow;  /* node row (guard j<193) */
    const int t    = lane;                   /* x-group: nodes 4t..4t+3 */
    const int np   = (z == 2) ? 3 : 4;       /* pairs in this group */
    const int nch  = np + 1;
    const int c0   = z * 4;

    __shared__ float areas[256];
    __shared__ float sred[4][10];
    areas[threadIdx.x] = area[threadIdx.x];
    __syncthreads();

    float numA = 0.f, denA = 0.f;
    float bceA[4] = {0.f, 0.f, 0.f, 0.f};
    float cntA[4] = {0.f, 0.f, 0.f, 0.f};

    const bool act = (j < NNODE) && (t < 48);

    if (act) {
        const int  y0 = (j >= 1) ? (j - 1) : 0;        /* clamped rows -> loads always valid */
        const int  y1 = (j <= NYX - 1) ? j : (NYX - 1);
        const int  xo = t * 4;

        float    sigP[2][6], bcvP[2][6], sigC[2][6], bcvC[2][6];
        unsigned w5P[2], w5C[2];

        for (int cc = 0; cc < nch; ++cc) {             /* wave-uniform runtime loop */
            const int ch = c0 + cc;
            const size_t base = (size_t)(b * NCH + ch) * (NYX * NYX);

            #pragma unroll
            for (int r = 0; r < 2; ++r) {
                const int  yy = r ? y1 : y0;
                const bool mm = r ? (j <= NYX - 1) : (j >= 1);
                const float4 p4 = *reinterpret_cast<const float4*>(pred   + base + (size_t)yy * NYX + xo);
                const float4 l4 = *reinterpret_cast<const float4*>(labels + base + (size_t)yy * NYX + xo);
                const float pe[4] = {p4.x, p4.y, p4.z, p4.w};
                const float le[4] = {l4.x, l4.y, l4.z, l4.w};
                unsigned bits = 0;
                #pragma unroll
                for (int e = 0; e < 4; ++e) {
                    const float pv = mm ? pe[e] : 0.f;     /* row-OOB -> padded zeros */
                    const float lv = mm ? le[e] : 0.f;
                    bits |= ((unsigned)lv) << e;
                    const float s = __builtin_amdgcn_rcpf(1.f + __expf(-pv));
                    sigC[r][e + 1] = mm ? s : 0.f;         /* pad AFTER sigmoid -> 0 */
                    bcvC[r][e + 1] = fmaxf(pv, 0.f) - pv * lv + __logf(1.f + __expf(-fabsf(pv)));
                }
                w5C[r] = bits << 1;
                sigC[r][5] = 0.f;        /* x = 4t+4 slot, used only by node 192 (x OOB) */
                bcvC[r][5] = LN2f;

                /* x = 4t-1 halo from lane-1 (lane 0 is the real x=0 border) */
                const float    sw = __shfl_up(sigC[r][4], 1);
                const float    bw = __shfl_up(bcvC[r][4], 1);
                const unsigned ww = (unsigned)__shfl_up((int)w5C[r], 1);
                sigC[r][0] = (t == 0) ? 0.f  : sw;
                bcvC[r][0] = (t == 0) ? LN2f : bw;
                w5C[r]    |= (t == 0) ? 0u   : ((ww >> 4) & 1u);
            }

            if (cc > 0) {
                const int pp = cc - 1;                   /* pair index within group */
                float pnum = 0.f, pden = 0.f, pbce = 0.f, pcnt = 0.f;
                #pragma unroll
                for (int i = 0; i < 5; ++i) {
                    if (i < 4 || t == 47) {              /* node ix=192 only on lane 47 */
                        const unsigned b0 = (w5P[0] >> i) & 1u, b1 = (w5P[0] >> (i + 1)) & 1u;
                        const unsigned b2 = (w5P[1] >> i) & 1u, b3 = (w5P[1] >> (i + 1)) & 1u;
                        const unsigned b4 = (w5C[0] >> i) & 1u, b5 = (w5C[0] >> (i + 1)) & 1u;
                        const unsigned b6 = (w5C[1] >> i) & 1u, b7 = (w5C[1] >> (i + 1)) & 1u;
                        const unsigned byte = b0 | (b1 << 1) | (b2 << 2) | (b3 << 3)
                                            | (b4 << 4) | (b5 << 5) | (b6 << 6) | (b7 << 7);
                        float d2 = 0.f;
                        {
                            const float e0 = sigP[0][i]     - (float)b0;
                            const float e1 = sigP[0][i + 1] - (float)b1;
                            const float e2 = sigP[1][i]     - (float)b2;
                            const float e3 = sigP[1][i + 1] - (float)b3;
                            const float e4 = sigC[0][i]     - (float)b4;
                            const float e5 = sigC[0][i + 1] - (float)b5;
                            const float e6 = sigC[1][i]     - (float)b6;
                            const float e7 = sigC[1][i + 1] - (float)b7;
                            d2 = ((e0*e0 + e1*e1) + (e2*e2 + e3*e3)) + ((e4*e4 + e5*e5) + (e6*e6 + e7*e7));
                        }
                        const float w  = 1.f - sqrtf(d2) * (1.f / 16.f);
                        const float la = areas[byte];
                        pnum += w * la;
                        pden += la;
                        const bool msk = (byte == 0u) || (byte == 255u);
                        if (msk) {
                            pcnt += 1.f;
                            pbce += ((bcvP[0][i] + bcvP[0][i+1]) + (bcvP[1][i] + bcvP[1][i+1]))
                                  + ((bcvC[0][i] + bcvC[0][i+1]) + (bcvC[1][i] + bcvC[1][i+1]));
                        }
                    }
                }
                numA += pnum; denA += pden;
                bceA[pp] += pbce; cntA[pp] += pcnt;
            }

            /* prev <- cur */
            #pragma unroll
            for (int r = 0; r < 2; ++r) {
                w5P[r] = w5C[r];
                #pragma unroll
                for (int q = 0; q < 6; ++q) { sigP[r][q] = sigC[r][q]; bcvP[r][q] = bcvC[r][q]; }
            }
        }
    }

    /* wave shuffle reduce of 10 values */
    float v[10] = {numA, denA, bceA[0], bceA[1], bceA[2], bceA[3], cntA[0], cntA[1], cntA[2], cntA[3]};
    #pragma unroll
    for (int off = 32; off > 0; off >>= 1) {
        #pragma unroll
        for (int q = 0; q < 10; ++q) v[q] += __shfl_down(v[q], off);
    }
    if (lane == 0) {
        #pragma unroll
        for (int q = 0; q < 10; ++q) sred[wrow][q] = v[q];
    }
    __syncthreads();
    if (threadIdx.x == 0) {
        float s[10];
        #pragma unroll
        for (int q = 0; q < 10; ++q)
            s[q] = ((sred[0][q] + sred[1][q]) + (sred[2][q] + sred[3][q]));
        float* rec = partials + (size_t)((z * NB + b) * NBLK + blockIdx.x) * RECF;
        #pragma unroll
        for (int q = 0; q < 10; ++q) rec[q] = s[q];
        rec[10] = 0.f; rec[11] = 0.f;
    }
}

__global__ __launch_bounds__(384) void sdice_final(const float* __restrict__ partials,
                                                   const float* __restrict__ area,
                                                   float* __restrict__ out)
{
    __shared__ float gs[NGRP][10];
    const int g    = threadIdx.x >> 6;      /* 6 waves, one per (z,b) group: g = z*NB+b */
    const int lane = threadIdx.x & 63;

    float v[10];
    #pragma unroll
    for (int q = 0; q < 10; ++q) v[q] = 0.f;
    if (lane < NBLK) {
        const float* rec = partials + (size_t)(g * NBLK + lane) * RECF;
        #pragma unroll
        for (int q = 0; q < 10; ++q) v[q] = rec[q];
    }
    #pragma unroll
    for (int off = 32; off > 0; off >>= 1) {
        #pragma unroll
        for (int q = 0; q < 10; ++q) v[q] += __shfl_down(v[q], off);
    }
    if (lane == 0) {
        #pragma unroll
        for (int q = 0; q < 10; ++q) gs[g][q] = v[q];
    }
    __syncthreads();

    if (threadIdx.x == 0) {
        const float a1 = area[1];   /* pred_byte == 1 everywhere (strict '>' in fori_loop) */
        float dice_sum = 0.f, vol_sum = 0.f;
        for (int b = 0; b < NB; ++b) {
            float numb = 0.f, denb = 0.f, volb = 0.f;
            for (int z = 0; z < NZ; ++z) {
                const int g2 = z * NB + b;
                const int np = (z == 2) ? 3 : 4;
                numb += 2.0f * gs[g2][0];
                denb += gs[g2][1];
                for (int pp = 0; pp < np; ++pp)
                    volb += gs[g2][2 + pp] / (8.0f * gs[g2][6 + pp]);
            }
            denb += (float)NPAIR * (float)L_NODES * a1;
            dice_sum += 1.0f - (numb + 0.001f) / (denb + 0.001f);
            vol_sum  += volb;
        }
        out[0] = dice_sum / (float)NB + vol_sum / (float)NB;
    }
}

extern "C" void kernel_launch(void* const* d_in, const int* in_sizes, int n_in,
                              void* d_out, int out_size, void* d_ws, size_t ws_size,
                              hipStream_t stream) {
    const float* pred   = (const float*)d_in[0];
    const float* labels = (const float*)d_in[1];
    const float* area   = (const float*)d_in[2];
    float* out  = (float*)d_out;
    float* part = (float*)d_ws;

    dim3 grid(NBLK, NB, NZ);
    sdice_node<<<grid, dim3(256), 0, stream>>>(pred, labels, area, part);
    sdice_final<<<1, 384, 0, stream>>>(part, area, out);
}